// Round 3
// baseline (270.240 us; speedup 1.0000x reference)
//
#include <hip/hip_runtime.h>

#define B_    16
#define Q_    300
#define S_    16
#define HID_  256
#define SSCALE 0.077f
// Only level 0 (H=W=100, start 0) and queries 0..2 ever reach the output:
// reference gathers emb[b, 0, ref_levels[b,q], s, c], ref_levels in {0,1,2}.

// One block per (b, qi, s-quad): computes 4 sampling points' bilinear
// samples, then h1 = tanh(g@w1+b1), off = h1@w2+b2, stores
// SSCALE*tanh(off) into off_table[b*3+qi][s][4].
// 192 blocks x 256 threads.
__global__ __launch_bounds__(256) void sample_mlp_kernel(
    const float* __restrict__ ref_polys,   // [B,Q,8]
    const float* __restrict__ memory,      // [B,13125,256]
    const float* __restrict__ w1,          // [256,256]
    const float* __restrict__ b1,          // [256]
    const float* __restrict__ w2,          // [256,4]
    const float* __restrict__ b2,          // [4]
    float* __restrict__ off_table)         // [B*3,16,4]
{
    const int blk = blockIdx.x;        // 0..191
    const int sq  = blk & 3;           // s-quad: s = sq*4 + i
    const int bq  = blk >> 2;          // 0..47 = b*3+qi
    const int b   = bq / 3;
    const int qi  = bq - b * 3;
    const int tid = threadIdx.x;       // channel

    __shared__ float4 gs4[HID_];       // gs4[k] = g[k] for the 4 samples
    __shared__ float  h1s[4][HID_];

    const float* rp = ref_polys + (size_t)(b * Q_ + qi) * 8;
    const float r0 = rp[0], r1 = rp[1], r2 = rp[2], r3 = rp[3];
    const float r4 = rp[4], r5 = rp[5], r6 = rp[6], r7 = rp[7];
    const float* mb = memory + (size_t)b * 13125 * 256;

    float gv[4];
    #pragma unroll
    for (int i = 0; i < 4; ++i) {
        const int s = sq * 4 + i;
        const float t = (float)s * (1.0f / 15.0f);
        const float spx = 2.0f * (((r0 * t + r1) * t + r2) * t + r3) - 1.0f;
        const float spy = 2.0f * (((r4 * t + r5) * t + r6) * t + r7) - 1.0f;

        // grid_sample align_corners=False, zeros padding, W=H=100
        const float x = (spx + 1.0f) * 50.0f - 0.5f;
        const float y = (spy + 1.0f) * 50.0f - 0.5f;
        const float x0f = floorf(x), y0f = floorf(y);
        const int   x0 = (int)x0f,  y0 = (int)y0f;
        const int   x1 = x0 + 1,    y1 = y0 + 1;
        const float wx1 = x - x0f, wx0 = 1.0f - wx1;
        const float wy1 = y - y0f, wy0 = 1.0f - wy1;
        const bool vx0 = (x0 >= 0) & (x0 < 100);
        const bool vx1 = (x1 >= 0) & (x1 < 100);
        const bool vy0 = (y0 >= 0) & (y0 < 100);
        const bool vy1 = (y1 >= 0) & (y1 < 100);
        const int cx0 = min(max(x0, 0), 99), cx1 = min(max(x1, 0), 99);
        const int cy0 = min(max(y0, 0), 99), cy1 = min(max(y1, 0), 99);
        const float w00 = (vx0 && vy0) ? wx0 * wy0 : 0.0f;
        const float w10 = (vx1 && vy0) ? wx1 * wy0 : 0.0f;
        const float w01 = (vx0 && vy1) ? wx0 * wy1 : 0.0f;
        const float w11 = (vx1 && vy1) ? wx1 * wy1 : 0.0f;

        gv[i] = w00 * mb[(size_t)(cy0 * 100 + cx0) * 256 + tid]
              + w10 * mb[(size_t)(cy0 * 100 + cx1) * 256 + tid]
              + w01 * mb[(size_t)(cy1 * 100 + cx0) * 256 + tid]
              + w11 * mb[(size_t)(cy1 * 100 + cx1) * 256 + tid];
    }
    gs4[tid] = make_float4(gv[0], gv[1], gv[2], gv[3]);
    __syncthreads();

    // ---- MLP layer 1: thread j computes h1[j] for all 4 samples ----
    const float bb = b1[tid];
    float a0 = bb, a1 = bb, a2 = bb, a3 = bb;
    const float* w1c = w1 + tid;          // column j, stride 256 (coalesced)
    #pragma unroll 8
    for (int k = 0; k < HID_; ++k) {
        const float w = w1c[(size_t)k * HID_];
        const float4 g = gs4[k];
        a0 += g.x * w;
        a1 += g.y * w;
        a2 += g.z * w;
        a3 += g.w * w;
    }
    h1s[0][tid] = tanhf(a0);
    h1s[1][tid] = tanhf(a1);
    h1s[2][tid] = tanhf(a2);
    h1s[3][tid] = tanhf(a3);
    __syncthreads();

    // ---- MLP layer 2: wave wv handles sample wv; butterfly reduce ----
    const int wv = tid >> 6;    // 0..3
    const int ln = tid & 63;
    float p0 = 0.f, p1 = 0.f, p2 = 0.f, p3 = 0.f;
    #pragma unroll
    for (int j = ln; j < HID_; j += 64) {
        const float h = h1s[wv][j];
        const float* w2r = w2 + j * 4;
        p0 += h * w2r[0];
        p1 += h * w2r[1];
        p2 += h * w2r[2];
        p3 += h * w2r[3];
    }
    #pragma unroll
    for (int off = 32; off; off >>= 1) {
        p0 += __shfl_down(p0, off);
        p1 += __shfl_down(p1, off);
        p2 += __shfl_down(p2, off);
        p3 += __shfl_down(p3, off);
    }
    if (ln == 0) {
        float* o = off_table + ((size_t)bq * 16 + sq * 4 + wv) * 4;
        o[0] = SSCALE * tanhf(p0 + b2[0]);
        o[1] = SSCALE * tanhf(p1 + b2[1]);
        o[2] = SSCALE * tanhf(p2 + b2[2]);
        o[3] = SSCALE * tanhf(p3 + b2[3]);
    }
}

// One thread per float2 of output (c=0,1 of one (s,np)).
// t*2 = (b*Q+q)*64 + s*4 + np*2  -> 32 threads per query.
__global__ __launch_bounds__(256) void out_kernel(
    const float* __restrict__ ref_polys,   // [B,Q,8]
    const int*   __restrict__ ref_levels,  // [B,Q]
    const float* __restrict__ off_table,   // [B*3,16,4]
    float2* __restrict__ out)              // [B*Q*32] float2
{
    const int t   = blockIdx.x * 256 + threadIdx.x;   // 0 .. 153599
    const int idx = t & 31;          // s*2 + np
    const int w   = t >> 5;          // b*Q + q
    const int b   = w / Q_;
    const int s   = idx >> 1;
    const int np  = idx & 1;

    const float* rp = ref_polys + (size_t)w * 8;
    const float tt  = (float)s * (1.0f / 15.0f);
    const float spx = 2.0f * (((rp[0] * tt + rp[1]) * tt + rp[2]) * tt + rp[3]) - 1.0f;
    const float spy = 2.0f * (((rp[4] * tt + rp[5]) * tt + rp[6]) * tt + rp[7]) - 1.0f;

    const int lvl = ref_levels[w];
    const float2 off = *(const float2*)(off_table
        + (((size_t)b * 3 + lvl) * 16 + s) * 4 + np * 2);
    out[t] = make_float2(off.x + spx, off.y + spy);
}

extern "C" void kernel_launch(void* const* d_in, const int* in_sizes, int n_in,
                              void* d_out, int out_size, void* d_ws, size_t ws_size,
                              hipStream_t stream) {
    const float* ref_polys  = (const float*)d_in[0];
    const float* memory     = (const float*)d_in[1];
    const float* w1         = (const float*)d_in[2];
    const float* b1         = (const float*)d_in[3];
    const float* w2         = (const float*)d_in[4];
    const float* b2         = (const float*)d_in[5];
    const int*   ref_levels = (const int*)d_in[6];
    float* out = (float*)d_out;

    float* off_table = (float*)d_ws;   // B*3*16*4 = 3072 floats = 12 KB

    // Stage 1: 768 sample points, 4 per block -> off_table
    sample_mlp_kernel<<<dim3(B_ * 3 * (S_ / 4)), dim3(256), 0, stream>>>(
        ref_polys, memory, w1, b1, w2, b2, off_table);

    // Stage 2: 307200 outputs as 153600 float2 = 600 blocks * 256
    out_kernel<<<dim3(600), dim3(256), 0, stream>>>(
        ref_polys, ref_levels, off_table, (float2*)out);
}